// Round 14
// baseline (181.699 us; speedup 1.0000x reference)
//
#include <hip/hip_runtime.h>
#include <hip/hip_bf16.h>
#include <math.h>

#define B 32
#define N 8400
#define M 60
#define C 80
#define INF_COST 1e8f
#define NPART 4
#define PLEN 2100    // N / NPART
#define PJ 9         // ceil(PLEN/256)

typedef unsigned long long u64;

// ---------- iou: bit-exact IEEE, identical codegen in all kernels ----------
__device__ __forceinline__ float iou_fn(
    float px1, float py1, float px2, float py2,
    float gx1, float gy1, float gx2, float gy2)
{
#pragma clang fp contract(off)
    float ltx = fmaxf(px1, gx1), lty = fmaxf(py1, gy1);
    float rbx = fminf(px2, gx2), rby = fminf(py2, gy2);
    float wx = fmaxf(rbx - ltx, 0.0f), wy = fmaxf(rby - lty, 0.0f);
    float inter = wx * wy;
    float a1 = (px2 - px1) * (py2 - py1);
    float a2 = (gx2 - gx1) * (gy2 - gy1);
    float uni = fmaxf(a1 + a2 - inter, 1e-6f);
    return inter / uni;
}

// ---------- cost: fast HW transcendentals; contract(off) pins identical bits ----------
__device__ __forceinline__ float cost_fast(
    float iou, float logit,
    float pcx, float pcy, float rstride,   // rstride = 1/stride (exact: pow2)
    float gcx, float gcy)
{
#pragma clang fp contract(off)
    const float LOG2_10 = 3.3219280948873623f;
    const float LOG2_E  = 1.4426950408889634f;
    const float LN_2    = 0.6931471805599453f;
    float dx = pcx - gcx, dy = pcy - gcy;
    float dist = __builtin_amdgcn_sqrtf(dx * dx + dy * dy) * rstride;
    float soft = __builtin_amdgcn_exp2f((dist - 3.0f) * LOG2_10);
    float iouc = __builtin_amdgcn_logf(iou + 1e-7f) * (-3.0f * LN_2);
    float e    = __builtin_amdgcn_exp2f(-logit * LOG2_E);
    float sig  = __builtin_amdgcn_rcpf(1.0f + e);
    float t    = __builtin_amdgcn_exp2f(-fabsf(logit) * LOG2_E);
    float sp   = __builtin_amdgcn_logf(1.0f + t) * LN_2;
    float bce  = fmaxf(logit, 0.0f) - logit * iou + sp;
    float scale = iou - sig;
    float cls  = bce * scale * scale;
    return (cls + iouc) + soft;
}

// ---------- kernel 1: valid_mask[b,n] ----------
__global__ __launch_bounds__(256) void k_valid(
    const float* __restrict__ priors,
    const float* __restrict__ gt_bboxes,
    const float* __restrict__ pad,
    unsigned char* __restrict__ valid)
{
    int idx = blockIdx.x * 256 + threadIdx.x;
    if (idx >= B * N) return;
    int b = idx / N, n = idx % N;
    float px = priors[n * 4 + 0];
    float py = priors[n * 4 + 1];
    const float* g = gt_bboxes + (size_t)b * M * 4;
    const float* pf = pad + (size_t)b * M;
    unsigned char v = 0;
    for (int m = 0; m < M; m++) {
        float x1 = g[m * 4 + 0], y1 = g[m * 4 + 1];
        float x2 = g[m * 4 + 2], y2 = g[m * 4 + 3];
        float mn = fminf(fminf(px - x1, py - y1), fminf(x2 - px, y2 - py));
        if (mn > 0.0f && pf[m] > 0.0f) { v = 1; break; }
    }
    valid[idx] = v;
}

// ---------- kernel 2a: per-(column, quarter) partial top-13 lists ----------
// grid = B*M*NPART; block handles 2100 contiguous n.
__global__ __launch_bounds__(256) void k_part(
    const float* __restrict__ pred_bboxes,
    const float* __restrict__ pred_scores,
    const float* __restrict__ priors,
    const int*   __restrict__ gt_labels,
    const float* __restrict__ gt_bboxes,
    const float* __restrict__ pad,
    const unsigned char* __restrict__ valid,
    float* __restrict__ PI, float* __restrict__ PC, int* __restrict__ PN)
{
    __shared__ u64      s_key[256];
    __shared__ u64      s_thr;
    __shared__ float    s_candv[160];    // provably <= 109
    __shared__ int      s_candn[160];
    __shared__ unsigned s_cnt;
    __shared__ float    s_slotv[13];
    __shared__ int      s_slotn[13];

    const int i = blockIdx.x;
    const int bm = i >> 2, part = i & 3;
    if (pad[bm] == 0.0f) return;         // merge also skips padded columns

    const int b = bm / M;
    const int tid = threadIdx.x;
    const int base = part * PLEN;

    const float4 g = ((const float4*)gt_bboxes)[bm];
    const float gx1 = g.x, gy1 = g.y, gx2 = g.z, gy2 = g.w;
    const float gcx = (gx1 + gx2) * 0.5f, gcy = (gy1 + gy2) * 0.5f;
    const int label = gt_labels[bm];
    const float4* pb4 = ((const float4*)pred_bboxes) + (size_t)b * N;
    const float* srow = pred_scores + (size_t)b * N * C;
    const unsigned char* vrow = valid + (size_t)b * N;
    const float4* pr4 = (const float4*)priors;

    float myi[PJ], myc[PJ];
    u64 minc = ~0ull, maxi = ~0ull;      // lex-min keys (every thread owns >=8 real items)

    // ---- fused scan: iou (compute) + cost (compute, gathered logit) ----
#pragma unroll
    for (int j = 0; j < PJ; ++j) {
        int off = tid + (j << 8);
        float v = 0.0f, c = 0.0f;
        if (off < PLEN) {
            int n = base + off;
            float4 p = pb4[n];
            v = iou_fn(p.x, p.y, p.z, p.w, gx1, gy1, gx2, gy2);
            if (vrow[n]) {
                float4 pr = pr4[n];
                c = cost_fast(v, srow[(size_t)n * C + label], pr.x, pr.y,
                              __builtin_amdgcn_rcpf(pr.z), gcx, gcy);
            } else c = INF_COST;
            u64 ck = ((u64)__float_as_uint(c) << 32) | (unsigned)n;              // cost asc, n asc
            if (ck < minc) minc = ck;
            u64 ik = ((u64)(0xFFFFFFFFu - __float_as_uint(v)) << 32) | (unsigned)n; // iou desc, n asc
            if (ik < maxi) maxi = ik;
        }
        myi[j] = v; myc[j] = c;
    }

    // ======== bottom-13 (cost, n) ========
    s_key[tid] = minc;
    if (tid == 0) s_cnt = 0;
    __syncthreads();
    {
        unsigned r = 0;
        for (int t = 0; t < 256; ++t) r += (s_key[t] < minc) ? 1u : 0u;
        if (r == 12u) s_thr = minc;              // keys unique: exactly one writer
    }
    __syncthreads();
    const u64 tc = s_thr;
    // candidates: key <= tc  (13 smallest items all have key <= tc; ng in [13, 109])
#pragma unroll
    for (int j = 0; j < PJ; ++j) {
        int off = tid + (j << 8);
        if (off < PLEN) {
            int n = base + off;
            u64 ck = ((u64)__float_as_uint(myc[j]) << 32) | (unsigned)n;
            if (ck <= tc) {
                unsigned p = atomicAdd(&s_cnt, 1u);
                s_candv[p] = myc[j]; s_candn[p] = n;
            }
        }
    }
    __syncthreads();
    {
        const unsigned nc = s_cnt;
        for (unsigned ii = tid; ii < nc; ii += 256) {
            float c = s_candv[ii]; int nn = s_candn[ii];
            unsigned r = 0;
            for (unsigned t = 0; t < nc; ++t) {
                float u = s_candv[t];
                r += (u < c || (u == c && s_candn[t] < nn)) ? 1u : 0u;
            }
            if (r < 13u) { s_slotv[r] = c; s_slotn[r] = nn; }
        }
    }
    __syncthreads();
    if (tid < 13) {
        int o = (bm * NPART + part) * 13 + tid;
        PC[o] = s_slotv[tid];
        PN[o] = s_slotn[tid];
    }
    if (tid == 0) s_cnt = 0;
    __syncthreads();

    // ======== top-13 iou (values only) ========
    s_key[tid] = maxi;
    __syncthreads();
    {
        unsigned r = 0;
        for (int t = 0; t < 256; ++t) r += (s_key[t] < maxi) ? 1u : 0u;
        if (r == 12u) s_thr = maxi;
    }
    __syncthreads();
    const u64 ti = s_thr;
#pragma unroll
    for (int j = 0; j < PJ; ++j) {
        int off = tid + (j << 8);
        if (off < PLEN) {
            int n = base + off;
            u64 ik = ((u64)(0xFFFFFFFFu - __float_as_uint(myi[j])) << 32) | (unsigned)n;
            if (ik <= ti) {
                unsigned p = atomicAdd(&s_cnt, 1u);
                s_candv[p] = myi[j]; s_candn[p] = n;
            }
        }
    }
    __syncthreads();
    {
        const unsigned ng = s_cnt;
        for (unsigned ii = tid; ii < ng; ii += 256) {
            float v = s_candv[ii]; int nn = s_candn[ii];
            unsigned r = 0;
            for (unsigned t = 0; t < ng; ++t) {
                float u = s_candv[t];
                r += (u > v || (u == v && s_candn[t] < nn)) ? 1u : 0u;
            }
            if (r < 13u) s_slotv[r] = v;
        }
    }
    __syncthreads();
    if (tid < 13) PI[(bm * NPART + part) * 13 + tid] = s_slotv[tid];
}

// ---------- kernel 2b: per-column 4-way merge (1 thread per column) ----------
__global__ __launch_bounds__(256) void k_merge(
    const float* __restrict__ pad,
    const float* __restrict__ PI,
    const float* __restrict__ PC,
    const int*   __restrict__ PN,
    float* __restrict__ cK, int* __restrict__ nK)
{
    int bm = blockIdx.x * 256 + threadIdx.x;
    if (bm >= B * M) return;
    if (pad[bm] == 0.0f) return;

    const float* pi = PI + (size_t)bm * 52;
    const float* pc = PC + (size_t)bm * 52;
    const int*   pn = PN + (size_t)bm * 52;

    // ---- iou: 4-way desc merge, descending-order sum (== top_k().sum()) ----
    int q0 = 0, q1 = 0, q2 = 0, q3 = 0;
    float ss = 0.0f;
    for (int r = 0; r < 13; ++r) {
        float v0 = (q0 < 13) ? pi[q0]      : -1.0f;
        float v1 = (q1 < 13) ? pi[13 + q1] : -1.0f;
        float v2 = (q2 < 13) ? pi[26 + q2] : -1.0f;
        float v3 = (q3 < 13) ? pi[39 + q3] : -1.0f;
        float bv = v0; int bw = 0;
        if (v1 > bv) { bv = v1; bw = 1; }
        if (v2 > bv) { bv = v2; bw = 2; }
        if (v3 > bv) { bv = v3; bw = 3; }
        ss += bv;                            // values >= 0; +0.0 fills are bitwise no-ops
        if (bw == 0) q0++; else if (bw == 1) q1++; else if (bw == 2) q2++; else q3++;
    }
    int K = (int)ss;                         // trunc == astype(int32)
    if (K < 1) K = 1;

    // ---- cost: 4-way asc lex merge; K-th element is the threshold pair ----
    q0 = q1 = q2 = q3 = 0;
    float ck = 0.0f; int nk = 0;
    for (int r = 0; r < K; ++r) {
        float c0 = (q0 < 13) ? pc[q0]      : INFINITY; int n0 = (q0 < 13) ? pn[q0]      : 0x7fffffff;
        float c1 = (q1 < 13) ? pc[13 + q1] : INFINITY; int n1 = (q1 < 13) ? pn[13 + q1] : 0x7fffffff;
        float c2 = (q2 < 13) ? pc[26 + q2] : INFINITY; int n2 = (q2 < 13) ? pn[26 + q2] : 0x7fffffff;
        float c3 = (q3 < 13) ? pc[39 + q3] : INFINITY; int n3 = (q3 < 13) ? pn[39 + q3] : 0x7fffffff;
        float bv = c0; int bn = n0, bw = 0;
        if (c1 < bv || (c1 == bv && n1 < bn)) { bv = c1; bn = n1; bw = 1; }
        if (c2 < bv || (c2 == bv && n2 < bn)) { bv = c2; bn = n2; bw = 2; }
        if (c3 < bv || (c3 == bv && n3 < bn)) { bv = c3; bn = n3; bw = 3; }
        ck = bv; nk = bn;
        if (bw == 0) q0++; else if (bw == 1) q1++; else if (bw == 2) q2++; else q3++;
    }
    cK[bm] = ck; nK[bm] = nk;
}

// ---------- kernel 3: per-(b,n) row; recomputes cost (bit-identical to k_part) ----------
__global__ __launch_bounds__(256) void k_assign(
    const float* __restrict__ pred_bboxes,
    const float* __restrict__ pred_scores,
    const float* __restrict__ priors,
    const int*   __restrict__ gt_labels,
    const float* __restrict__ gt_bboxes,
    const float* __restrict__ pad,
    const unsigned char* __restrict__ valid,
    const float* __restrict__ cK,
    const int*   __restrict__ nK,
    float* __restrict__ out)
{
    __shared__ float s_box[M][4];
    __shared__ float s_gc[M][2];
    __shared__ float s_ck[M];
    __shared__ int   s_lab[M];
    __shared__ int   s_nk[M];
    __shared__ unsigned char s_gtv[M];

    const int cidx = blockIdx.x;
    const int b = cidx / 33;
    const int chunk = cidx % 33;
    const int n = chunk * 256 + threadIdx.x;

    if (threadIdx.x < M) {
        int m = threadIdx.x, gi = b * M + m;
        float4 g = ((const float4*)gt_bboxes)[gi];
        s_box[m][0] = g.x; s_box[m][1] = g.y; s_box[m][2] = g.z; s_box[m][3] = g.w;
        s_gc[m][0] = (g.x + g.z) * 0.5f;
        s_gc[m][1] = (g.y + g.w) * 0.5f;
        s_ck[m] = cK[gi];
        s_lab[m] = gt_labels[gi];
        s_nk[m] = nK[gi];
        s_gtv[m] = (pad[gi] > 0.0f) ? 1 : 0;
    }
    __syncthreads();
    if (n >= N) return;

    const size_t idx = (size_t)b * N + n;
    const float4 p = ((const float4*)pred_bboxes)[idx];
    const float4 pr = ((const float4*)priors)[n];
    const float rst = __builtin_amdgcn_rcpf(pr.z);
    const int vn = valid[idx];
    const float* scores = pred_scores + idx * C;

    int count = 0, firstm = -1;
    float minc = INFINITY; int amin = 0;
    float firstiou = 0.0f, aminiou = 0.0f;

#pragma unroll 4
    for (int m = 0; m < M; m++) {
        float iou = iou_fn(p.x, p.y, p.z, p.w,
                           s_box[m][0], s_box[m][1], s_box[m][2], s_box[m][3]);
        float c;
        if (vn) {
            float logit = scores[s_lab[m]];
            c = cost_fast(iou, logit, pr.x, pr.y, rst, s_gc[m][0], s_gc[m][1]);
        } else {
            c = INF_COST;
        }
        if (c < minc) { minc = c; amin = m; aminiou = iou; }  // first-min, like jnp.argmin
        float ckm = s_ck[m]; int nkm = s_nk[m];
        bool matched = s_gtv[m] && (c < ckm || (c == ckm && n <= nkm));
        if (matched) { count++; if (firstm < 0) { firstm = m; firstiou = iou; } }
    }

    int mstar; float mi;
    if (count > 1)       { mstar = amin;   mi = aminiou; }
    else if (count == 1) { mstar = firstm; mi = firstiou; }
    else                 { mstar = -1;     mi = 0.0f; }

    float* o_lab = out;
    float* o_w   = out + (size_t)B * N;
    float* o_box = out + (size_t)2 * B * N;
    float* o_met = out + (size_t)6 * B * N;
    o_w[idx] = 1.0f;
    if (mstar >= 0) {
        o_lab[idx] = (float)s_lab[mstar];
        o_box[idx * 4 + 0] = s_box[mstar][0];
        o_box[idx * 4 + 1] = s_box[mstar][1];
        o_box[idx * 4 + 2] = s_box[mstar][2];
        o_box[idx * 4 + 3] = s_box[mstar][3];
        o_met[idx] = mi;
    } else {
        o_lab[idx] = (float)C;
        o_box[idx * 4 + 0] = 0.0f;
        o_box[idx * 4 + 1] = 0.0f;
        o_box[idx * 4 + 2] = 0.0f;
        o_box[idx * 4 + 3] = 0.0f;
        o_met[idx] = 0.0f;
    }
}

extern "C" void kernel_launch(void* const* d_in, const int* in_sizes, int n_in,
                              void* d_out, int out_size, void* d_ws, size_t ws_size,
                              hipStream_t stream) {
    const float* pred_bboxes = (const float*)d_in[0];
    const float* pred_scores = (const float*)d_in[1];
    const float* priors      = (const float*)d_in[2];
    const int*   gt_labels   = (const int*)d_in[3];
    const float* gt_bboxes   = (const float*)d_in[4];
    const float* pad         = (const float*)d_in[5];
    float* out = (float*)d_out;

    unsigned char* ws = (unsigned char*)d_ws;
    size_t off = 0;
    unsigned char* valid = ws;                  off += (size_t)B * N;          // 268800
    float* cKp = (float*)(ws + off);            off += (size_t)B * M * 4;
    int*   nKp = (int*)(ws + off);              off += (size_t)B * M * 4;
    float* PI  = (float*)(ws + off);            off += (size_t)B * M * NPART * 13 * 4;
    float* PC  = (float*)(ws + off);            off += (size_t)B * M * NPART * 13 * 4;
    int*   PN  = (int*)(ws + off);              off += (size_t)B * M * NPART * 13 * 4;

    k_valid<<<(B * N + 255) / 256, 256, 0, stream>>>(priors, gt_bboxes, pad, valid);
    k_part <<<B * M * NPART, 256, 0, stream>>>(pred_bboxes, pred_scores, priors, gt_labels,
                                               gt_bboxes, pad, valid, PI, PC, PN);
    k_merge<<<(B * M + 255) / 256, 256, 0, stream>>>(pad, PI, PC, PN, cKp, nKp);
    k_assign<<<33 * B, 256, 0, stream>>>(pred_bboxes, pred_scores, priors, gt_labels,
                                         gt_bboxes, pad, valid, cKp, nKp, out);
}

// Round 15
// 137.941 us; speedup vs baseline: 1.3172x; 1.3172x over previous
//
#include <hip/hip_runtime.h>
#include <hip/hip_bf16.h>
#include <math.h>

#define B 32
#define N 8400
#define M 60
#define C 80
#define INF_COST 1e8f
#define NPART 4
#define PLEN 2100    // N / NPART
#define PJ 9         // ceil(PLEN/256)

typedef unsigned long long u64;

// ---------- iou: bit-exact IEEE, identical codegen in all kernels ----------
__device__ __forceinline__ float iou_fn(
    float px1, float py1, float px2, float py2,
    float gx1, float gy1, float gx2, float gy2)
{
#pragma clang fp contract(off)
    float ltx = fmaxf(px1, gx1), lty = fmaxf(py1, gy1);
    float rbx = fminf(px2, gx2), rby = fminf(py2, gy2);
    float wx = fmaxf(rbx - ltx, 0.0f), wy = fmaxf(rby - lty, 0.0f);
    float inter = wx * wy;
    float a1 = (px2 - px1) * (py2 - py1);
    float a2 = (gx2 - gx1) * (gy2 - gy1);
    float uni = fmaxf(a1 + a2 - inter, 1e-6f);
    return inter / uni;
}

// ---------- cost: fast HW transcendentals; contract(off) pins identical bits ----------
__device__ __forceinline__ float cost_fast(
    float iou, float logit,
    float pcx, float pcy, float rstride,   // rstride = 1/stride (exact: pow2)
    float gcx, float gcy)
{
#pragma clang fp contract(off)
    const float LOG2_10 = 3.3219280948873623f;
    const float LOG2_E  = 1.4426950408889634f;
    const float LN_2    = 0.6931471805599453f;
    float dx = pcx - gcx, dy = pcy - gcy;
    float dist = __builtin_amdgcn_sqrtf(dx * dx + dy * dy) * rstride;
    float soft = __builtin_amdgcn_exp2f((dist - 3.0f) * LOG2_10);
    float iouc = __builtin_amdgcn_logf(iou + 1e-7f) * (-3.0f * LN_2);
    float e    = __builtin_amdgcn_exp2f(-logit * LOG2_E);
    float sig  = __builtin_amdgcn_rcpf(1.0f + e);
    float t    = __builtin_amdgcn_exp2f(-fabsf(logit) * LOG2_E);
    float sp   = __builtin_amdgcn_logf(1.0f + t) * LN_2;
    float bce  = fmaxf(logit, 0.0f) - logit * iou + sp;
    float scale = iou - sig;
    float cls  = bce * scale * scale;
    return (cls + iouc) + soft;
}

// ---------- wave-wide bitonic sort (ascending across 64 lanes) ----------
__device__ __forceinline__ u64 wave_sort_asc(u64 key, int lane)
{
#pragma unroll
    for (int k = 2; k <= 64; k <<= 1) {
#pragma unroll
        for (int j = k >> 1; j > 0; j >>= 1) {
            u64 o = __shfl_xor((unsigned long long)key, j);
            bool keepmin = ((lane & k) == 0) == ((lane & j) == 0);
            bool take = (o < key) == keepmin;
            if (take) key = o;
        }
    }
    return key;
}

// ---------- kernel 1: valid_mask[b,n] ----------
__global__ __launch_bounds__(256) void k_valid(
    const float* __restrict__ priors,
    const float* __restrict__ gt_bboxes,
    const float* __restrict__ pad,
    unsigned char* __restrict__ valid)
{
    int idx = blockIdx.x * 256 + threadIdx.x;
    if (idx >= B * N) return;
    int b = idx / N, n = idx % N;
    float px = priors[n * 4 + 0];
    float py = priors[n * 4 + 1];
    const float* g = gt_bboxes + (size_t)b * M * 4;
    const float* pf = pad + (size_t)b * M;
    unsigned char v = 0;
    for (int m = 0; m < M; m++) {
        float x1 = g[m * 4 + 0], y1 = g[m * 4 + 1];
        float x2 = g[m * 4 + 2], y2 = g[m * 4 + 3];
        float mn = fminf(fminf(px - x1, py - y1), fminf(x2 - px, y2 - py));
        if (mn > 0.0f && pf[m] > 0.0f) { v = 1; break; }
    }
    valid[idx] = v;
}

// ---------- kernel 2a: per-(column, quarter) partial 13-lists ----------
__global__ __launch_bounds__(256) void k_part(
    const float* __restrict__ pred_bboxes,
    const float* __restrict__ pred_scores,
    const float* __restrict__ priors,
    const int*   __restrict__ gt_labels,
    const float* __restrict__ gt_bboxes,
    const float* __restrict__ pad,
    const unsigned char* __restrict__ valid,
    float* __restrict__ PI, float* __restrict__ PC, int* __restrict__ PN)
{
    __shared__ u64      s_ckey[4][13];   // per-wave sorted 13-prefix of cost thread-minima
    __shared__ u64      s_ikey[4][13];   // per-wave sorted 13-prefix of iou  thread-maxima keys
    __shared__ u64      s_thr[2];
    __shared__ float    s_cv[160]; __shared__ int s_cn[160];   // cost candidates (<=109)
    __shared__ float    s_iv[160]; __shared__ int s_in[160];   // iou  candidates (<=109)
    __shared__ unsigned s_cnt[2];
    __shared__ float    s_slotc[13]; __shared__ int s_slotn[13];
    __shared__ float    s_sloti[13];

    const int i = blockIdx.x;
    const int bm = i >> 2, part = i & 3;
    if (pad[bm] == 0.0f) return;         // merge also skips padded columns

    const int b = bm / M;
    const int tid = threadIdx.x;
    const int lane = tid & 63;
    const int w = tid >> 6;
    const int base = part * PLEN;

    if (tid == 0) { s_cnt[0] = 0; s_cnt[1] = 0; }

    const float4 g = ((const float4*)gt_bboxes)[bm];
    const float gx1 = g.x, gy1 = g.y, gx2 = g.z, gy2 = g.w;
    const float gcx = (gx1 + gx2) * 0.5f, gcy = (gy1 + gy2) * 0.5f;
    const int label = gt_labels[bm];
    const float4* pb4 = ((const float4*)pred_bboxes) + (size_t)b * N;
    const float* srow = pred_scores + (size_t)b * N * C;
    const unsigned char* vrow = valid + (size_t)b * N;
    const float4* pr4 = (const float4*)priors;

    float myi[PJ], myc[PJ];
    u64 minc = ~0ull, maxi = ~0ull;      // lex-min keys; every thread owns >=8 real items

    // ---- fused scan: iou (compute) + cost (compute, gathered logit) ----
#pragma unroll
    for (int j = 0; j < PJ; ++j) {
        int off = tid + (j << 8);
        float v = 0.0f, c = 0.0f;
        if (off < PLEN) {
            int n = base + off;
            float4 p = pb4[n];
            v = iou_fn(p.x, p.y, p.z, p.w, gx1, gy1, gx2, gy2);
            if (vrow[n]) {
                float4 pr = pr4[n];
                c = cost_fast(v, srow[(size_t)n * C + label], pr.x, pr.y,
                              __builtin_amdgcn_rcpf(pr.z), gcx, gcy);
            } else c = INF_COST;
            u64 ck = ((u64)__float_as_uint(c) << 32) | (unsigned)n;               // cost asc, n asc
            if (ck < minc) minc = ck;
            u64 ik = ((u64)(0xFFFFFFFFu - __float_as_uint(v)) << 32) | (unsigned)n; // iou desc, n asc
            if (ik < maxi) maxi = ik;
        }
        myi[j] = v; myc[j] = c;
    }

    // ---- wave bitonic sorts: 13-prefix of thread-minima per wave ----
    {
        u64 sc = wave_sort_asc(minc, lane);
        if (lane < 13) s_ckey[w][lane] = sc;
        u64 si = wave_sort_asc(maxi, lane);
        if (lane < 13) s_ikey[w][lane] = si;
    }
    __syncthreads();                     // B1

    // ---- 4-way merge of sorted prefixes -> 13th smallest thread-min (2 threads, parallel) ----
    if (tid < 2) {
        const u64 (*L)[13] = (tid == 0) ? s_ckey : s_ikey;
        int q0 = 0, q1 = 0, q2 = 0, q3 = 0;
        u64 t = 0;
        for (int r = 0; r < 13; ++r) {
            u64 v0 = L[0][q0], v1 = L[1][q1], v2 = L[2][q2], v3 = L[3][q3];
            u64 bv = v0; int bw = 0;
            if (v1 < bv) { bv = v1; bw = 1; }
            if (v2 < bv) { bv = v2; bw = 2; }
            if (v3 < bv) { bv = v3; bw = 3; }
            t = bv;
            if (bw == 0) q0++; else if (bw == 1) q1++; else if (bw == 2) q2++; else q3++;
        }
        s_thr[tid] = t;
    }
    __syncthreads();                     // B2
    const u64 tc = s_thr[0];
    const u64 ti = s_thr[1];

    // ---- push candidates: key <= threshold (provably 13 <= cnt <= 109) ----
#pragma unroll
    for (int j = 0; j < PJ; ++j) {
        int off = tid + (j << 8);
        if (off < PLEN) {
            int n = base + off;
            u64 ck = ((u64)__float_as_uint(myc[j]) << 32) | (unsigned)n;
            if (ck <= tc) {
                unsigned p = atomicAdd(&s_cnt[0], 1u);
                if (p < 160u) { s_cv[p] = myc[j]; s_cn[p] = n; }
            }
            u64 ik = ((u64)(0xFFFFFFFFu - __float_as_uint(myi[j])) << 32) | (unsigned)n;
            if (ik <= ti) {
                unsigned p = atomicAdd(&s_cnt[1], 1u);
                if (p < 160u) { s_iv[p] = myi[j]; s_in[p] = n; }
            }
        }
    }
    __syncthreads();                     // B3

    // ---- parallel ranks: cost on waves 0-1, iou on waves 2-3 (concurrent) ----
    {
        const unsigned nc = s_cnt[0], ng = s_cnt[1];
        if (tid < 128) {
            unsigned ii = tid;
            if (ii < nc) {
                float c = s_cv[ii]; int nn = s_cn[ii];
                unsigned r = 0;
                for (unsigned t = 0; t < nc; ++t) {
                    float u = s_cv[t];
                    r += (u < c || (u == c && s_cn[t] < nn)) ? 1u : 0u;
                }
                if (r < 13u) { s_slotc[r] = c; s_slotn[r] = nn; }
            }
        } else {
            unsigned ii = tid - 128;
            if (ii < ng) {
                float v = s_iv[ii]; int nn = s_in[ii];
                unsigned r = 0;
                for (unsigned t = 0; t < ng; ++t) {
                    float u = s_iv[t];
                    r += (u > v || (u == v && s_in[t] < nn)) ? 1u : 0u;
                }
                if (r < 13u) s_sloti[r] = v;
            }
        }
    }
    __syncthreads();                     // B4

    if (tid < 13) {
        int o = (bm * NPART + part) * 13 + tid;
        PC[o] = s_slotc[tid];
        PN[o] = s_slotn[tid];
        PI[o] = s_sloti[tid];
    }
}

// ---------- kernel 2b: per-column 4-way merge (1 thread per column) ----------
__global__ __launch_bounds__(256) void k_merge(
    const float* __restrict__ pad,
    const float* __restrict__ PI,
    const float* __restrict__ PC,
    const int*   __restrict__ PN,
    float* __restrict__ cK, int* __restrict__ nK)
{
    int bm = blockIdx.x * 256 + threadIdx.x;
    if (bm >= B * M) return;
    if (pad[bm] == 0.0f) return;

    const float* pi = PI + (size_t)bm * 52;
    const float* pc = PC + (size_t)bm * 52;
    const int*   pn = PN + (size_t)bm * 52;

    // ---- iou: 4-way desc merge, descending-order sum (== top_k().sum()) ----
    int q0 = 0, q1 = 0, q2 = 0, q3 = 0;
    float ss = 0.0f;
    for (int r = 0; r < 13; ++r) {
        float v0 = (q0 < 13) ? pi[q0]      : -1.0f;
        float v1 = (q1 < 13) ? pi[13 + q1] : -1.0f;
        float v2 = (q2 < 13) ? pi[26 + q2] : -1.0f;
        float v3 = (q3 < 13) ? pi[39 + q3] : -1.0f;
        float bv = v0; int bw = 0;
        if (v1 > bv) { bv = v1; bw = 1; }
        if (v2 > bv) { bv = v2; bw = 2; }
        if (v3 > bv) { bv = v3; bw = 3; }
        ss += bv;                            // values >= 0; +0.0 fills are bitwise no-ops
        if (bw == 0) q0++; else if (bw == 1) q1++; else if (bw == 2) q2++; else q3++;
    }
    int K = (int)ss;                         // trunc == astype(int32)
    if (K < 1) K = 1;

    // ---- cost: 4-way asc lex merge; K-th element is the threshold pair ----
    q0 = q1 = q2 = q3 = 0;
    float ck = 0.0f; int nk = 0;
    for (int r = 0; r < K; ++r) {
        float c0 = (q0 < 13) ? pc[q0]      : INFINITY; int n0 = (q0 < 13) ? pn[q0]      : 0x7fffffff;
        float c1 = (q1 < 13) ? pc[13 + q1] : INFINITY; int n1 = (q1 < 13) ? pn[13 + q1] : 0x7fffffff;
        float c2 = (q2 < 13) ? pc[26 + q2] : INFINITY; int n2 = (q2 < 13) ? pn[26 + q2] : 0x7fffffff;
        float c3 = (q3 < 13) ? pc[39 + q3] : INFINITY; int n3 = (q3 < 13) ? pn[39 + q3] : 0x7fffffff;
        float bv = c0; int bn = n0, bw = 0;
        if (c1 < bv || (c1 == bv && n1 < bn)) { bv = c1; bn = n1; bw = 1; }
        if (c2 < bv || (c2 == bv && n2 < bn)) { bv = c2; bn = n2; bw = 2; }
        if (c3 < bv || (c3 == bv && n3 < bn)) { bv = c3; bn = n3; bw = 3; }
        ck = bv; nk = bn;
        if (bw == 0) q0++; else if (bw == 1) q1++; else if (bw == 2) q2++; else q3++;
    }
    cK[bm] = ck; nK[bm] = nk;
}

// ---------- kernel 3: per-(b,n) row; recomputes cost (bit-identical to k_part) ----------
__global__ __launch_bounds__(256) void k_assign(
    const float* __restrict__ pred_bboxes,
    const float* __restrict__ pred_scores,
    const float* __restrict__ priors,
    const int*   __restrict__ gt_labels,
    const float* __restrict__ gt_bboxes,
    const float* __restrict__ pad,
    const unsigned char* __restrict__ valid,
    const float* __restrict__ cK,
    const int*   __restrict__ nK,
    float* __restrict__ out)
{
    __shared__ float s_box[M][4];
    __shared__ float s_gc[M][2];
    __shared__ float s_ck[M];
    __shared__ int   s_lab[M];
    __shared__ int   s_nk[M];
    __shared__ unsigned char s_gtv[M];

    const int cidx = blockIdx.x;
    const int b = cidx / 33;
    const int chunk = cidx % 33;
    const int n = chunk * 256 + threadIdx.x;

    if (threadIdx.x < M) {
        int m = threadIdx.x, gi = b * M + m;
        float4 g = ((const float4*)gt_bboxes)[gi];
        s_box[m][0] = g.x; s_box[m][1] = g.y; s_box[m][2] = g.z; s_box[m][3] = g.w;
        s_gc[m][0] = (g.x + g.z) * 0.5f;
        s_gc[m][1] = (g.y + g.w) * 0.5f;
        s_ck[m] = cK[gi];
        s_lab[m] = gt_labels[gi];
        s_nk[m] = nK[gi];
        s_gtv[m] = (pad[gi] > 0.0f) ? 1 : 0;
    }
    __syncthreads();
    if (n >= N) return;

    const size_t idx = (size_t)b * N + n;
    const float4 p = ((const float4*)pred_bboxes)[idx];
    const int vn = valid[idx];

    float* o_lab = out;
    float* o_w   = out + (size_t)B * N;
    float* o_box = out + (size_t)2 * B * N;
    float* o_met = out + (size_t)6 * B * N;

    int count = 0, firstm = -1;
    int mstar; float mi;

    if (!vn) {
        // all costs are exactly INF_COST: no gathers, no transcendentals
#pragma unroll
        for (int m = 0; m < M; m++) {
            float ckm = s_ck[m]; int nkm = s_nk[m];
            bool matched = s_gtv[m] &&
                           (INF_COST < ckm || (INF_COST == ckm && n <= nkm));
            if (matched) { count++; if (firstm < 0) firstm = m; }
        }
        // argmin over equal costs = 0 (first-min); used only when count > 1
        mstar = (count > 1) ? 0 : firstm;
        mi = 0.0f;
        if (mstar >= 0)
            mi = iou_fn(p.x, p.y, p.z, p.w,
                        s_box[mstar][0], s_box[mstar][1], s_box[mstar][2], s_box[mstar][3]);
    } else {
        const float4 pr = ((const float4*)priors)[n];
        const float rst = __builtin_amdgcn_rcpf(pr.z);
        const float* scores = pred_scores + idx * C;

        float minc = INFINITY; int amin = 0;
        float firstiou = 0.0f, aminiou = 0.0f;

        for (int mc = 0; mc < 4; ++mc) {
            float lg[15];
#pragma unroll
            for (int t = 0; t < 15; ++t) lg[t] = scores[s_lab[mc * 15 + t]];  // 15 loads in flight
#pragma unroll
            for (int t = 0; t < 15; ++t) {
                int m = mc * 15 + t;
                float iou = iou_fn(p.x, p.y, p.z, p.w,
                                   s_box[m][0], s_box[m][1], s_box[m][2], s_box[m][3]);
                float c = cost_fast(iou, lg[t], pr.x, pr.y, rst, s_gc[m][0], s_gc[m][1]);
                if (c < minc) { minc = c; amin = m; aminiou = iou; }  // first-min
                float ckm = s_ck[m]; int nkm = s_nk[m];
                bool matched = s_gtv[m] && (c < ckm || (c == ckm && n <= nkm));
                if (matched) { count++; if (firstm < 0) { firstm = m; firstiou = iou; } }
            }
        }
        if (count > 1)       { mstar = amin;   mi = aminiou; }
        else if (count == 1) { mstar = firstm; mi = firstiou; }
        else                 { mstar = -1;     mi = 0.0f; }
    }

    o_w[idx] = 1.0f;
    if (mstar >= 0) {
        o_lab[idx] = (float)s_lab[mstar];
        o_box[idx * 4 + 0] = s_box[mstar][0];
        o_box[idx * 4 + 1] = s_box[mstar][1];
        o_box[idx * 4 + 2] = s_box[mstar][2];
        o_box[idx * 4 + 3] = s_box[mstar][3];
        o_met[idx] = mi;
    } else {
        o_lab[idx] = (float)C;
        o_box[idx * 4 + 0] = 0.0f;
        o_box[idx * 4 + 1] = 0.0f;
        o_box[idx * 4 + 2] = 0.0f;
        o_box[idx * 4 + 3] = 0.0f;
        o_met[idx] = 0.0f;
    }
}

extern "C" void kernel_launch(void* const* d_in, const int* in_sizes, int n_in,
                              void* d_out, int out_size, void* d_ws, size_t ws_size,
                              hipStream_t stream) {
    const float* pred_bboxes = (const float*)d_in[0];
    const float* pred_scores = (const float*)d_in[1];
    const float* priors      = (const float*)d_in[2];
    const int*   gt_labels   = (const int*)d_in[3];
    const float* gt_bboxes   = (const float*)d_in[4];
    const float* pad         = (const float*)d_in[5];
    float* out = (float*)d_out;

    unsigned char* ws = (unsigned char*)d_ws;
    size_t off = 0;
    unsigned char* valid = ws;                  off += (size_t)B * N;
    float* cKp = (float*)(ws + off);            off += (size_t)B * M * 4;
    int*   nKp = (int*)(ws + off);              off += (size_t)B * M * 4;
    float* PI  = (float*)(ws + off);            off += (size_t)B * M * NPART * 13 * 4;
    float* PC  = (float*)(ws + off);            off += (size_t)B * M * NPART * 13 * 4;
    int*   PN  = (int*)(ws + off);              off += (size_t)B * M * NPART * 13 * 4;

    k_valid<<<(B * N + 255) / 256, 256, 0, stream>>>(priors, gt_bboxes, pad, valid);
    k_part <<<B * M * NPART, 256, 0, stream>>>(pred_bboxes, pred_scores, priors, gt_labels,
                                               gt_bboxes, pad, valid, PI, PC, PN);
    k_merge<<<(B * M + 255) / 256, 256, 0, stream>>>(pad, PI, PC, PN, cKp, nKp);
    k_assign<<<33 * B, 256, 0, stream>>>(pred_bboxes, pred_scores, priors, gt_labels,
                                         gt_bboxes, pad, valid, cKp, nKp, out);
}